// Round 1
// baseline (221.601 us; speedup 1.0000x reference)
//
#include <hip/hip_runtime.h>
#include <stdint.h>

// Problem constants (B=8, K=4, N=131072)
#define NTOT      4194304LL   // B*K*N
#define CHUNK     2048        // elements per block
#define NBLK      2048        // NTOT / CHUNK
#define NEG_PAD   (-1000.0f)
#define NEG_IDLE  (-100000000.0f)

typedef unsigned long long u64;
typedef float float4u __attribute__((ext_vector_type(4), aligned(4)));   // dwordx4, 4-B align
typedef float float3u __attribute__((ext_vector_type(3), aligned(4)));   // dwordx3, loads 12 B
typedef float float4a __attribute__((ext_vector_type(4), aligned(16)));
typedef int   int4v   __attribute__((ext_vector_type(4), aligned(16)));

// Lookback publication: totals[bid] = s(23:0) | a<<24 (47:24) | TAG<<48.
// TAG has two distinct bytes -> cannot be produced by any repeated-byte
// poison pattern; a 16 KB memset node zeroes flags every launch anyway.
#define TAG       0x4D17ULL
#define VALMASK   0xFFFFFFFFFFFFULL   // low 48 bits (counts, tag stripped)

// ---------------------------------------------------------------------------
// Fused single-pass kernel (was K1 + K2), decoupled-lookback global prefix:
//   phase 1: read masks once (nontemporal int4), build per-8-elem bitmasks in
//            registers/LDS, block scan, publish tagged block totals (agent-
//            scope release store).
//   lookback: predicated spin-sum of predecessors' totals (8 per thread,
//            same shape as the old K2 predicated sum; L2/L3-hot 16 KB).
//   phase 2: identical expand structure to the verified K2 (rgb LDS tile +
//            coalesced float4; ls/la window gather + in-register select),
//            but all output stores nontemporal so 84 MB of streaming writes
//            stop evicting the ~3 MB/XCD gather working set from L2.
// ---------------------------------------------------------------------------
__global__ __launch_bounds__(256, 6) void fused_kernel(
    const float* __restrict__ rgb, const float* __restrict__ lsurf,
    const float* __restrict__ lair, const float* __restrict__ idle,
    const int* __restrict__ ms, const int* __restrict__ ma,
    u64* __restrict__ totals,
    unsigned rgb_max, unsigned ts_max, unsigned ta_max,
    float* __restrict__ out_rgb, float* __restrict__ out_ls, float* __restrict__ out_la)
{
    __shared__ unsigned wsum[4];
    __shared__ u64 wacc[4];
    __shared__ unsigned packLDS[256];   // u16 pack per 8 elements
    __shared__ unsigned prefLDS[256];   // packed exclusive prefix (s | a<<16)
    __shared__ float    rgbLDS[3072];   // 12 KB: 4 rounds of 256*3 floats

    const int t = threadIdx.x, lane = t & 63, wave = t >> 6;
    const unsigned bid = blockIdx.x;
    const long long base = (long long)bid * CHUNK;

    // ---- phase 1: masks -> pack bits (read ONCE, zero reuse -> nontemporal)
    const int4v* ms4 = (const int4v*)(ms + base);
    const int4v* ma4 = (const int4v*)(ma + base);
    int4v s0 = __builtin_nontemporal_load(ms4 + 2 * t);
    int4v s1 = __builtin_nontemporal_load(ms4 + 2 * t + 1);
    int4v a0 = __builtin_nontemporal_load(ma4 + 2 * t);
    int4v a1 = __builtin_nontemporal_load(ma4 + 2 * t + 1);
    unsigned sbits = (unsigned)(s0[0] != 0)        | ((unsigned)(s0[1] != 0) << 1)
                   | ((unsigned)(s0[2] != 0) << 2) | ((unsigned)(s0[3] != 0) << 3)
                   | ((unsigned)(s1[0] != 0) << 4) | ((unsigned)(s1[1] != 0) << 5)
                   | ((unsigned)(s1[2] != 0) << 6) | ((unsigned)(s1[3] != 0) << 7);
    unsigned abits = (unsigned)(a0[0] != 0)        | ((unsigned)(a0[1] != 0) << 1)
                   | ((unsigned)(a0[2] != 0) << 2) | ((unsigned)(a0[3] != 0) << 3)
                   | ((unsigned)(a1[0] != 0) << 4) | ((unsigned)(a1[1] != 0) << 5)
                   | ((unsigned)(a1[2] != 0) << 6) | ((unsigned)(a1[3] != 0) << 7);
    unsigned pk = sbits | (abits << 8);
    const float idle_v = idle[(int)(base >> 17)];     // chunk lies in one (b,k) row

    packLDS[t] = pk;
    unsigned cnt = __popc(sbits) | (__popc(abits) << 16);

    unsigned x = cnt;                                 // wave-inclusive scan
    #pragma unroll
    for (int o = 1; o < 64; o <<= 1) {
        unsigned y = __shfl_up(x, o, 64);
        if (lane >= o) x += y;
    }
    if (lane == 63) wsum[wave] = x;
    __syncthreads();

    // ---- publish this block's tagged totals ASAP (before our own lookback)
    if (t == 0) {
        unsigned tot = wsum[0] + wsum[1] + wsum[2] + wsum[3];   // s | a<<16
        u64 val = (u64)(tot & 0xffffu) | ((u64)(tot >> 16) << 24) | (TAG << 48);
        __hip_atomic_store(&totals[bid], val, __ATOMIC_RELEASE,
                           __HIP_MEMORY_SCOPE_AGENT);
    }
    unsigned pre = (wave > 0 ? wsum[0] : 0u) + (wave > 1 ? wsum[1] : 0u)
                 + (wave > 2 ? wsum[2] : 0u);
    prefLDS[t] = pre + x - cnt;                       // per-pack exclusive (packed)

    // ---- decoupled lookback: spin-sum predecessors' totals (8 per thread).
    // Publication precedes any spin in program order; dispatch is in ID
    // order, so every predecessor publishes without waiting on us. Spin cap
    // turns a hypothetical ordering violation into a verify-fail, not a hang.
    unsigned pend = 0;
    #pragma unroll
    for (int j = 0; j < 8; ++j)
        if ((unsigned)t * 8u + (unsigned)j < bid) pend |= 1u << j;
    u64 acc = 0;
    for (int spin = 0; pend && spin < (1 << 16); ++spin) {
        #pragma unroll
        for (int j = 0; j < 8; ++j) {
            if ((pend >> j) & 1u) {
                u64 v = __hip_atomic_load(&totals[(unsigned)t * 8u + (unsigned)j],
                                          __ATOMIC_RELAXED, __HIP_MEMORY_SCOPE_AGENT);
                if ((v >> 48) == TAG) { acc += v & VALMASK; pend &= ~(1u << j); }
            }
        }
    }
    #pragma unroll
    for (int o = 32; o; o >>= 1) acc += __shfl_down(acc, o, 64);
    if (lane == 0) wacc[wave] = acc;
    __syncthreads();
    u64 basesum = wacc[0] + wacc[1] + wacc[2] + wacc[3];
    const unsigned excS = (unsigned)(basesum & 0xFFFFFFULL);
    const unsigned excA = (unsigned)((basesum >> 24) & 0xFFFFFFULL);

    // ---- phase 2: expand (identical structure to verified K2) ----
    const float alive     = 1.0f - idle_v;
    const float idle_term = idle_v * NEG_IDLE;
    const int  sub = t >> 3, b = t & 7;
    const unsigned bm = (1u << b) - 1u;
    const int  hp = t >> 1;                // pack within half for ls/la ownership
    const unsigned nib = (unsigned)(t & 1) * 4u;
    const unsigned nm  = (1u << nib) - 1u;

    #pragma unroll
    for (int h = 0; h < 2; ++h) {
        // ---- rgb: 4 rounds of 256, one dwordx3 gather each, into LDS tile ----
        #pragma unroll
        for (int r = 0; r < 4; ++r) {
            const int g = h * 4 + r;
            const int p = (g << 5) + sub;
            unsigned w  = packLDS[p];
            unsigned pv = prefLDS[p];
            unsigned rs = excS + (pv & 0xffffu) + __popc(w & bm);
            const int li = r * 768 + 3 * t;           // banks 3t%32: 2-way, free
            if ((w >> b) & 1u) {
                unsigned pr = rs < rgb_max ? rs : rgb_max;   // _expand's clip
                float3u v = *(const float3u*)(rgb + 3LL * pr);
                rgbLDS[li]     = v.x * alive;
                rgbLDS[li + 1] = v.y * alive;
                rgbLDS[li + 2] = v.z * alive;
            } else {
                rgbLDS[li] = 0.f; rgbLDS[li + 1] = 0.f; rgbLDS[li + 2] = 0.f;
            }
        }
        // ---- ls/la: 4 consecutive elements, window gather + select ----
        {
            const int p = h * 128 + hp;
            unsigned w  = packLDS[p];
            unsigned pv = prefLDS[p];
            unsigned ws = w & 0xffu, wa = (w >> 8) & 0xffu;
            unsigned r0s = excS + (pv & 0xffffu) + __popc(ws & nm);
            unsigned r0a = excA + (pv >> 16)     + __popc(wa & nm);
            unsigned sb = (ws >> nib) & 0xFu;
            unsigned ab = (wa >> nib) & 0xFu;
            unsigned rbs = r0s < ts_max - 3u ? r0s : ts_max - 3u;
            unsigned rba = r0a < ta_max - 3u ? r0a : ta_max - 3u;
            float4u Ws = *(const float4u*)(lsurf + rbs);   // covers ranks rbs..rbs+3
            float4u Wa = *(const float4u*)(lair  + rba);
            float lsv[4], lav[4];
            #pragma unroll
            for (int j = 0; j < 4; ++j) {
                unsigned mj = (1u << j) - 1u;
                unsigned rj = r0s + __popc(sb & mj);
                unsigned cs = (rj < ts_max ? rj : ts_max) - rbs;   // 0..3
                float vs = cs == 0 ? Ws.x : cs == 1 ? Ws.y : cs == 2 ? Ws.z : Ws.w;
                lsv[j] = ((sb >> j) & 1u) ? vs * alive + idle_term : NEG_PAD;
                unsigned rk = r0a + __popc(ab & mj);
                unsigned ca = (rk < ta_max ? rk : ta_max) - rba;
                float va = ca == 0 ? Wa.x : ca == 1 ? Wa.y : ca == 2 ? Wa.z : Wa.w;
                lav[j] = ((ab >> j) & 1u) ? va * alive + idle_term : NEG_PAD;
            }
            const long long eb = base + h * 1024 + 4 * t;  // 16-B aligned
            float4a vls; vls.x = lsv[0]; vls.y = lsv[1]; vls.z = lsv[2]; vls.w = lsv[3];
            float4a vla; vla.x = lav[0]; vla.y = lav[1]; vla.z = lav[2]; vla.w = lav[3];
            __builtin_nontemporal_store(vls, (float4a*)(out_ls + eb));
            __builtin_nontemporal_store(vla, (float4a*)(out_la + eb));
        }
        __syncthreads();                              // rgb tile complete
        float4a* dst = (float4a*)(out_rgb + 3 * base) + h * 768;
        const float4a* src = (const float4a*)rgbLDS;
        __builtin_nontemporal_store(src[t],       dst + t);
        __builtin_nontemporal_store(src[t + 256], dst + t + 256);
        __builtin_nontemporal_store(src[t + 512], dst + t + 512);
        __syncthreads();                              // tile reusable
    }
}

extern "C" void kernel_launch(void* const* d_in, const int* in_sizes, int n_in,
                              void* d_out, int out_size, void* d_ws, size_t ws_size,
                              hipStream_t stream)
{
    const float* rgb   = (const float*)d_in[0];
    const float* lsurf = (const float*)d_in[1];
    const float* lair  = (const float*)d_in[2];
    const float* idle  = (const float*)d_in[3];
    const int*   ms    = (const int*)d_in[4];   // bool -> int32 per harness contract
    const int*   ma    = (const int*)d_in[5];

    unsigned rgb_max = (unsigned)(in_sizes[0] / 3 - 1);
    unsigned ts_max  = (unsigned)(in_sizes[1] - 1);
    unsigned ta_max  = (unsigned)(in_sizes[2] - 1);

    float* out     = (float*)d_out;
    float* out_rgb = out;                  // (B,K,N,3)
    float* out_ls  = out + NTOT * 3;       // (B,K,N,1)
    float* out_la  = out_ls + NTOT;        // (B,K,N,1)

    // Workspace: 16 KB of tagged block totals. Zeroed each launch (memset
    // node is graph-capturable) so no flag can pre-exist; the distinct-byte
    // TAG additionally guards against any repeated-byte poison pattern.
    u64* totals = (u64*)d_ws;
    hipMemsetAsync(totals, 0, NBLK * sizeof(u64), stream);
    fused_kernel<<<NBLK, 256, 0, stream>>>(rgb, lsurf, lair, idle, ms, ma, totals,
                                           rgb_max, ts_max, ta_max,
                                           out_rgb, out_ls, out_la);
}

// Round 2
// 150.047 us; speedup vs baseline: 1.4769x; 1.4769x over previous
//
#include <hip/hip_runtime.h>
#include <stdint.h>

// Problem constants (B=8, K=4, N=131072)
#define NTOT      4194304LL   // B*K*N
#define CHUNK     2048        // elements per block
#define NBLK      2048        // NTOT / CHUNK
#define NEG_PAD   (-1000.0f)
#define NEG_IDLE  (-100000000.0f)
#define CAPS      832         // per-block dense-stage capacity (mean 614, +10.5 sigma)
#define CAPA      832

typedef unsigned long long u64;
typedef float float3u __attribute__((ext_vector_type(3), aligned(4)));   // dwordx3 fallback gather
typedef float float4a __attribute__((ext_vector_type(4), aligned(16)));
typedef int   int4v   __attribute__((ext_vector_type(4), aligned(16)));

// ---------------------------------------------------------------------------
// K1: read masks ONCE (nontemporal int4); emit per-8-element compressed
// bitmasks (u16: sbits | abits<<8) and per-block packed totals (s | a<<32).
// ---------------------------------------------------------------------------
__global__ __launch_bounds__(256, 8) void count_kernel(
    const int* __restrict__ ms, const int* __restrict__ ma,
    unsigned short* __restrict__ cmp, u64* __restrict__ totals)
{
    const int t = threadIdx.x, lane = t & 63, wave = t >> 6;
    const unsigned bid = blockIdx.x;
    const long long base = (long long)bid * CHUNK;

    const int4v* ms4 = (const int4v*)(ms + base);
    const int4v* ma4 = (const int4v*)(ma + base);
    int4v s0 = __builtin_nontemporal_load(ms4 + 2 * t);
    int4v s1 = __builtin_nontemporal_load(ms4 + 2 * t + 1);
    int4v a0 = __builtin_nontemporal_load(ma4 + 2 * t);
    int4v a1 = __builtin_nontemporal_load(ma4 + 2 * t + 1);
    unsigned sbits = (unsigned)(s0[0] != 0)        | ((unsigned)(s0[1] != 0) << 1)
                   | ((unsigned)(s0[2] != 0) << 2) | ((unsigned)(s0[3] != 0) << 3)
                   | ((unsigned)(s1[0] != 0) << 4) | ((unsigned)(s1[1] != 0) << 5)
                   | ((unsigned)(s1[2] != 0) << 6) | ((unsigned)(s1[3] != 0) << 7);
    unsigned abits = (unsigned)(a0[0] != 0)        | ((unsigned)(a0[1] != 0) << 1)
                   | ((unsigned)(a0[2] != 0) << 2) | ((unsigned)(a0[3] != 0) << 3)
                   | ((unsigned)(a1[0] != 0) << 4) | ((unsigned)(a1[1] != 0) << 5)
                   | ((unsigned)(a1[2] != 0) << 6) | ((unsigned)(a1[3] != 0) << 7);

    cmp[bid * 256u + (unsigned)t] = (unsigned short)(sbits | (abits << 8));

    unsigned cnt = __popc(sbits) | (__popc(abits) << 16);
    #pragma unroll
    for (int o = 32; o; o >>= 1) cnt += __shfl_down(cnt, o, 64);
    __shared__ unsigned lds[4];
    if (lane == 0) lds[wave] = cnt;
    __syncthreads();
    if (t == 0) {
        unsigned tot = lds[0] + lds[1] + lds[2] + lds[3];
        totals[bid] = (u64)(tot & 0xffffu) | ((u64)(tot >> 16) << 32);
    }
}

// ---------------------------------------------------------------------------
// K2: per-pack prefixes via one block scan; block base via predicated sum of
// the 16 KB totals array (L2-hot). NEW: stage each block's dense source
// slices (rgb[excS..excS+totS), lsurf[...], lair[excA..)) into LDS with
// perfectly-coalesced sequential dword loads (exact bytes, read once), then
// all per-element picks are conflict-free LDS reads. Outputs: rgb via 12 KB
// LDS tile -> coalesced nontemporal float4; ls/la per-thread 4-element
// nontemporal float4. Per-element global fallback covers the (never-taken
// in this input) CAPS overflow case.
// ---------------------------------------------------------------------------
__global__ __launch_bounds__(256, 5) void expand_kernel(
    const float* __restrict__ rgb, const float* __restrict__ lsurf,
    const float* __restrict__ lair, const float* __restrict__ idle,
    const unsigned short* __restrict__ cmp, const u64* __restrict__ totals,
    unsigned rgb_max, unsigned ts_max, unsigned ta_max,
    float* __restrict__ out_rgb, float* __restrict__ out_ls, float* __restrict__ out_la)
{
    __shared__ unsigned wsum[4];
    __shared__ u64 wacc[4];
    __shared__ unsigned packLDS[256];     // u16 pack per 8 elements
    __shared__ unsigned prefLDS[256];     // packed exclusive local prefix (s | a<<16)
    __shared__ float    rgbLDS[3072];     // 12 KB output staging: 4 rounds of 256*3
    __shared__ float    rgbSrc[CAPS * 3]; // dense surface rgb slice
    __shared__ float    lsS[CAPS];        // dense surface logits slice
    __shared__ float    laS[CAPA];        // dense air logits slice

    const int t = threadIdx.x, lane = t & 63, wave = t >> 6;
    const unsigned bid = blockIdx.x;
    const long long base = (long long)bid * CHUNK;

    // --- independent loads first ---
    unsigned pk = cmp[bid * 256u + (unsigned)t];
    u64 acc = 0;
    #pragma unroll
    for (int j = 0; j < 8; ++j) {
        unsigned idx = (unsigned)t * 8u + (unsigned)j;
        acc += (idx < bid) ? totals[idx] : 0ULL;
    }
    const float idle_v = idle[(int)(base >> 17)];     // chunk lies in one (b,k) row

    packLDS[t] = pk;
    unsigned cnt = __popc(pk & 0xffu) | (__popc(pk >> 8) << 16);

    unsigned x = cnt;                                 // wave-inclusive scan
    #pragma unroll
    for (int o = 1; o < 64; o <<= 1) {
        unsigned y = __shfl_up(x, o, 64);
        if (lane >= o) x += y;
    }
    if (lane == 63) wsum[wave] = x;
    #pragma unroll
    for (int o = 32; o; o >>= 1) acc += __shfl_down(acc, o, 64);
    if (lane == 0) wacc[wave] = acc;
    __syncthreads();
    unsigned pre = (wave > 0 ? wsum[0] : 0u) + (wave > 1 ? wsum[1] : 0u)
                 + (wave > 2 ? wsum[2] : 0u);
    prefLDS[t] = pre + x - cnt;                       // per-pack exclusive (packed)
    u64 basesum = wacc[0] + wacc[1] + wacc[2] + wacc[3];
    const unsigned excS = (unsigned)(basesum & 0xffffffffULL);
    const unsigned excA = (unsigned)(basesum >> 32);
    unsigned totPk = wsum[0] + wsum[1] + wsum[2] + wsum[3];
    const unsigned totS = totPk & 0xffffu;
    const unsigned totA = totPk >> 16;

    // ---- dense source staging: sequential, fully-coalesced, read-once ----
    {
        const unsigned nS = totS < CAPS ? totS : CAPS;
        const unsigned nA = totA < CAPA ? totA : CAPA;
        const float* rgbB = rgb + 3LL * excS;
        const float* lsB  = lsurf + excS;
        const float* laB  = lair + excA;
        for (unsigned i = t; i < nS * 3u; i += 256u) rgbSrc[i] = rgbB[i];
        for (unsigned i = t; i < nS; i += 256u)      lsS[i]   = lsB[i];
        for (unsigned i = t; i < nA; i += 256u)      laS[i]   = laB[i];
    }
    __syncthreads();

    const float alive     = 1.0f - idle_v;
    const float idle_term = idle_v * NEG_IDLE;
    const int  sub = t >> 3, b = t & 7;
    const unsigned bm = (1u << b) - 1u;
    const int  hp = t >> 1;                // pack within half for ls/la ownership
    const unsigned nib = (unsigned)(t & 1) * 4u;
    const unsigned nm  = (1u << nib) - 1u;

    #pragma unroll
    for (int h = 0; h < 2; ++h) {
        // ---- rgb: 4 rounds of 256, LDS-sourced, into output staging tile ----
        #pragma unroll
        for (int r = 0; r < 4; ++r) {
            const int g = h * 4 + r;
            const int p = (g << 5) + sub;
            unsigned w  = packLDS[p];
            unsigned pv = prefLDS[p];
            const int li = r * 768 + 3 * t;           // banks 3t%32: 2-way, free
            if ((w >> b) & 1u) {
                unsigned lr = (pv & 0xffffu) + __popc(w & bm);   // local rank
                float vx, vy, vz;
                if (lr < CAPS) {
                    vx = rgbSrc[3 * lr]; vy = rgbSrc[3 * lr + 1]; vz = rgbSrc[3 * lr + 2];
                } else {                                // never-taken overflow path
                    unsigned pr = excS + lr; pr = pr < rgb_max ? pr : rgb_max;
                    float3u v = *(const float3u*)(rgb + 3LL * pr);
                    vx = v.x; vy = v.y; vz = v.z;
                }
                rgbLDS[li]     = vx * alive;
                rgbLDS[li + 1] = vy * alive;
                rgbLDS[li + 2] = vz * alive;
            } else {
                rgbLDS[li] = 0.f; rgbLDS[li + 1] = 0.f; rgbLDS[li + 2] = 0.f;
            }
        }
        // ---- ls/la: 4 consecutive elements, direct LDS picks ----
        {
            const int p = h * 128 + hp;
            unsigned w  = packLDS[p];
            unsigned pv = prefLDS[p];
            unsigned ws = w & 0xffu, wa = (w >> 8) & 0xffu;
            unsigned baseS = (pv & 0xffffu) + __popc(ws & nm);   // local rank of elem 0
            unsigned baseA = (pv >> 16)     + __popc(wa & nm);
            unsigned sb = (ws >> nib) & 0xFu;
            unsigned ab = (wa >> nib) & 0xFu;
            float lsv[4], lav[4];
            #pragma unroll
            for (int j = 0; j < 4; ++j) {
                unsigned mj = (1u << j) - 1u;
                unsigned rs = baseS + __popc(sb & mj);
                float vs = rs < CAPS ? lsS[rs]
                         : lsurf[(excS + rs) < ts_max ? (excS + rs) : ts_max];
                lsv[j] = ((sb >> j) & 1u) ? vs * alive + idle_term : NEG_PAD;
                unsigned ra = baseA + __popc(ab & mj);
                float va = ra < CAPA ? laS[ra]
                         : lair[(excA + ra) < ta_max ? (excA + ra) : ta_max];
                lav[j] = ((ab >> j) & 1u) ? va * alive + idle_term : NEG_PAD;
            }
            const long long eb = base + h * 1024 + 4 * t;  // 16-B aligned
            float4a vls; vls.x = lsv[0]; vls.y = lsv[1]; vls.z = lsv[2]; vls.w = lsv[3];
            float4a vla; vla.x = lav[0]; vla.y = lav[1]; vla.z = lav[2]; vla.w = lav[3];
            __builtin_nontemporal_store(vls, (float4a*)(out_ls + eb));
            __builtin_nontemporal_store(vla, (float4a*)(out_la + eb));
        }
        __syncthreads();                              // rgb tile complete
        float4a* dst = (float4a*)(out_rgb + 3 * base) + h * 768;
        const float4a* src = (const float4a*)rgbLDS;
        __builtin_nontemporal_store(src[t],       dst + t);
        __builtin_nontemporal_store(src[t + 256], dst + t + 256);
        __builtin_nontemporal_store(src[t + 512], dst + t + 512);
        __syncthreads();                              // tile reusable
    }
}

extern "C" void kernel_launch(void* const* d_in, const int* in_sizes, int n_in,
                              void* d_out, int out_size, void* d_ws, size_t ws_size,
                              hipStream_t stream)
{
    const float* rgb   = (const float*)d_in[0];
    const float* lsurf = (const float*)d_in[1];
    const float* lair  = (const float*)d_in[2];
    const float* idle  = (const float*)d_in[3];
    const int*   ms    = (const int*)d_in[4];   // bool -> int32 per harness contract
    const int*   ma    = (const int*)d_in[5];

    unsigned rgb_max = (unsigned)(in_sizes[0] / 3 - 1);
    unsigned ts_max  = (unsigned)(in_sizes[1] - 1);
    unsigned ta_max  = (unsigned)(in_sizes[2] - 1);

    float* out     = (float*)d_out;
    float* out_rgb = out;                  // (B,K,N,3)
    float* out_ls  = out + NTOT * 3;       // (B,K,N,1)
    float* out_la  = out_ls + NTOT;        // (B,K,N,1)

    // Workspace: totals (16 KB) then compressed masks (1 MB); both fully
    // rewritten by K1 every launch -> no init needed despite 0xAA poison.
    u64* totals = (u64*)d_ws;
    unsigned short* cmp = (unsigned short*)((char*)d_ws + 16384);

    count_kernel<<<NBLK, 256, 0, stream>>>(ms, ma, cmp, totals);
    expand_kernel<<<NBLK, 256, 0, stream>>>(rgb, lsurf, lair, idle, cmp, totals,
                                            rgb_max, ts_max, ta_max,
                                            out_rgb, out_ls, out_la);
}

// Round 3
// 140.775 us; speedup vs baseline: 1.5742x; 1.0659x over previous
//
#include <hip/hip_runtime.h>
#include <stdint.h>

// Problem constants (B=8, K=4, N=131072)
#define NTOT      4194304LL   // B*K*N
#define CHUNK     2048        // elements per block
#define NBLK      2048        // NTOT / CHUNK
#define NEG_PAD   (-1000.0f)
#define NEG_IDLE  (-100000000.0f)
#define CAPS      768         // per-block dense-stage capacity (mean 614, +7.4 sigma)
#define CAPA      768

typedef unsigned long long u64;
typedef float float3u __attribute__((ext_vector_type(3), aligned(4)));   // dwordx3 fallback gather
typedef float float4a __attribute__((ext_vector_type(4), aligned(16)));
typedef int   int4v   __attribute__((ext_vector_type(4), aligned(16)));

// ---------------------------------------------------------------------------
// K1: read masks ONCE (nontemporal int4); emit per-8-element compressed
// bitmasks (u16: sbits | abits<<8) and per-block packed totals (s | a<<32).
// ---------------------------------------------------------------------------
__global__ __launch_bounds__(256, 8) void count_kernel(
    const int* __restrict__ ms, const int* __restrict__ ma,
    unsigned short* __restrict__ cmp, u64* __restrict__ totals)
{
    const int t = threadIdx.x, lane = t & 63, wave = t >> 6;
    const unsigned bid = blockIdx.x;
    const long long base = (long long)bid * CHUNK;

    const int4v* ms4 = (const int4v*)(ms + base);
    const int4v* ma4 = (const int4v*)(ma + base);
    int4v s0 = __builtin_nontemporal_load(ms4 + 2 * t);
    int4v s1 = __builtin_nontemporal_load(ms4 + 2 * t + 1);
    int4v a0 = __builtin_nontemporal_load(ma4 + 2 * t);
    int4v a1 = __builtin_nontemporal_load(ma4 + 2 * t + 1);
    unsigned sbits = (unsigned)(s0[0] != 0)        | ((unsigned)(s0[1] != 0) << 1)
                   | ((unsigned)(s0[2] != 0) << 2) | ((unsigned)(s0[3] != 0) << 3)
                   | ((unsigned)(s1[0] != 0) << 4) | ((unsigned)(s1[1] != 0) << 5)
                   | ((unsigned)(s1[2] != 0) << 6) | ((unsigned)(s1[3] != 0) << 7);
    unsigned abits = (unsigned)(a0[0] != 0)        | ((unsigned)(a0[1] != 0) << 1)
                   | ((unsigned)(a0[2] != 0) << 2) | ((unsigned)(a0[3] != 0) << 3)
                   | ((unsigned)(a1[0] != 0) << 4) | ((unsigned)(a1[1] != 0) << 5)
                   | ((unsigned)(a1[2] != 0) << 6) | ((unsigned)(a1[3] != 0) << 7);

    cmp[bid * 256u + (unsigned)t] = (unsigned short)(sbits | (abits << 8));

    unsigned cnt = __popc(sbits) | (__popc(abits) << 16);
    #pragma unroll
    for (int o = 32; o; o >>= 1) cnt += __shfl_down(cnt, o, 64);
    __shared__ unsigned lds[4];
    if (lane == 0) lds[wave] = cnt;
    __syncthreads();
    if (t == 0) {
        unsigned tot = lds[0] + lds[1] + lds[2] + lds[3];
        totals[bid] = (u64)(tot & 0xffffu) | ((u64)(tot >> 16) << 32);
    }
}

// ---------------------------------------------------------------------------
// K2: per-pack prefixes via one block scan; block base via predicated sum of
// the 16 KB totals array (L2-hot). Dense source slices staged into LDS with
// float4 loads (aligned raw windows, exact bounds). Outputs all nontemporal,
// rgb stored DIRECTLY (3 dword NT stores/thread, wave spans contiguous
// 768 B -> L2 write-combines to full lines) -- no 12 KB output tile, no
// extra barriers. LDS 17.5 KB -> 8 blocks/CU (32 waves). 2 barriers total.
// Per-element global fallback covers the (never-taken) CAPS overflow.
// ---------------------------------------------------------------------------
__global__ __launch_bounds__(256, 8) void expand_kernel(
    const float* __restrict__ rgb, const float* __restrict__ lsurf,
    const float* __restrict__ lair, const float* __restrict__ idle,
    const unsigned short* __restrict__ cmp, const u64* __restrict__ totals,
    unsigned rgb_max, unsigned ts_max, unsigned ta_max,
    float* __restrict__ out_rgb, float* __restrict__ out_ls, float* __restrict__ out_la)
{
    __shared__ unsigned wsum[4];
    __shared__ u64 wacc[4];
    __shared__ unsigned packLDS[256];     // u16 pack per 8 elements
    __shared__ unsigned prefLDS[256];     // packed exclusive local prefix (s | a<<16)
    __shared__ float4a rgbSrc4[(CAPS * 3 + 4 + 3) / 4];   // 9232 B raw window
    __shared__ float4a lsS4[(CAPS + 4 + 3) / 4];          // 3088 B
    __shared__ float4a laS4[(CAPA + 4 + 3) / 4];          // 3088 B
    float* const rgbSrc = (float*)rgbSrc4;
    float* const lsS    = (float*)lsS4;
    float* const laS    = (float*)laS4;

    const int t = threadIdx.x, lane = t & 63, wave = t >> 6;
    const unsigned bid = blockIdx.x;
    const long long base = (long long)bid * CHUNK;

    // --- independent loads first ---
    unsigned pk = cmp[bid * 256u + (unsigned)t];
    u64 acc = 0;
    #pragma unroll
    for (int j = 0; j < 8; ++j) {
        unsigned idx = (unsigned)t * 8u + (unsigned)j;
        acc += (idx < bid) ? totals[idx] : 0ULL;
    }
    const float idle_v = idle[(int)(base >> 17)];     // chunk lies in one (b,k) row

    packLDS[t] = pk;
    unsigned cnt = __popc(pk & 0xffu) | (__popc(pk >> 8) << 16);

    unsigned x = cnt;                                 // wave-inclusive scan
    #pragma unroll
    for (int o = 1; o < 64; o <<= 1) {
        unsigned y = __shfl_up(x, o, 64);
        if (lane >= o) x += y;
    }
    if (lane == 63) wsum[wave] = x;
    #pragma unroll
    for (int o = 32; o; o >>= 1) acc += __shfl_down(acc, o, 64);
    if (lane == 0) wacc[wave] = acc;
    __syncthreads();
    unsigned pre = (wave > 0 ? wsum[0] : 0u) + (wave > 1 ? wsum[1] : 0u)
                 + (wave > 2 ? wsum[2] : 0u);
    prefLDS[t] = pre + x - cnt;                       // per-pack exclusive (packed)
    u64 basesum = wacc[0] + wacc[1] + wacc[2] + wacc[3];
    const unsigned excS = (unsigned)(basesum & 0xffffffffULL);
    const unsigned excA = (unsigned)(basesum >> 32);
    unsigned totPk = wsum[0] + wsum[1] + wsum[2] + wsum[3];
    const unsigned totS = totPk & 0xffffu;
    const unsigned totA = totPk >> 16;

    // ---- dense source staging: float4 over aligned raw windows, read-once.
    // Window [ab, ab+F): ab = 16B-aligned start, ofs = element offset inside.
    // All accesses stay within [start_of_slice_rounded_down, end_of_slice):
    // never past the logical end of any input array.
    const unsigned nS = totS < CAPS ? totS : CAPS;
    const unsigned nA = totA < CAPA ? totA : CAPA;
    const unsigned ofsR = (excS * 3u) & 3u;
    const unsigned ofsS = excS & 3u;
    const unsigned ofsA = excA & 3u;
    {
        const unsigned FR = ofsR + nS * 3u, nvR = FR >> 2, tlR = FR & 3u;
        const unsigned FS = ofsS + nS,      nvS = FS >> 2, tlS = FS & 3u;
        const unsigned FA = ofsA + nA,      nvA = FA >> 2, tlA = FA & 3u;
        const float4a* sR = (const float4a*)(rgb + (excS * 3u - ofsR));
        const float4a* sS = (const float4a*)(lsurf + (excS - ofsS));
        const float4a* sA = (const float4a*)(lair + (excA - ofsA));
        for (unsigned i = t; i < nvR; i += 256u)
            rgbSrc4[i] = __builtin_nontemporal_load(sR + i);
        for (unsigned i = t; i < nvS; i += 256u)
            lsS4[i] = __builtin_nontemporal_load(sS + i);
        for (unsigned i = t; i < nvA; i += 256u)
            laS4[i] = __builtin_nontemporal_load(sA + i);
        if ((unsigned)t < tlR) rgbSrc[4u * nvR + t] = rgb[excS * 3u - ofsR + 4u * nvR + t];
        if ((unsigned)t < tlS) lsS[4u * nvS + t]    = lsurf[excS - ofsS + 4u * nvS + t];
        if ((unsigned)t < tlA) laS[4u * nvA + t]    = lair[excA - ofsA + 4u * nvA + t];
    }
    __syncthreads();

    const float alive     = 1.0f - idle_v;
    const float idle_term = idle_v * NEG_IDLE;
    const int  sub = t >> 3, b = t & 7;
    const unsigned bm = (1u << b) - 1u;
    const int  hp = t >> 1;                // pack within half for ls/la ownership
    const unsigned nib = (unsigned)(t & 1) * 4u;
    const unsigned nm  = (1u << nib) - 1u;

    // ---- rgb: 8 rounds of 256 elements; element = g*256 + t; direct NT stores
    #pragma unroll
    for (int g = 0; g < 8; ++g) {
        const int p = (g << 5) + sub;
        unsigned w  = packLDS[p];
        unsigned pv = prefLDS[p];
        const long long e = base + g * 256 + t;
        float vx = 0.f, vy = 0.f, vz = 0.f;
        if ((w >> b) & 1u) {
            unsigned lr = (pv & 0xffffu) + __popc(w & bm);   // local rank
            if (lr < CAPS) {
                vx = rgbSrc[ofsR + 3u * lr];
                vy = rgbSrc[ofsR + 3u * lr + 1u];
                vz = rgbSrc[ofsR + 3u * lr + 2u];
            } else {                                // never-taken overflow path
                unsigned pr = excS + lr; pr = pr < rgb_max ? pr : rgb_max;
                float3u v = *(const float3u*)(rgb + 3LL * pr);
                vx = v.x; vy = v.y; vz = v.z;
            }
            vx *= alive; vy *= alive; vz *= alive;
        }
        __builtin_nontemporal_store(vx, out_rgb + 3 * e);
        __builtin_nontemporal_store(vy, out_rgb + 3 * e + 1);
        __builtin_nontemporal_store(vz, out_rgb + 3 * e + 2);
    }

    // ---- ls/la: 4 consecutive elements per thread, LDS picks, NT float4 ----
    #pragma unroll
    for (int h = 0; h < 2; ++h) {
        const int p = h * 128 + hp;
        unsigned w  = packLDS[p];
        unsigned pv = prefLDS[p];
        unsigned ws = w & 0xffu, wa = (w >> 8) & 0xffu;
        unsigned baseS = (pv & 0xffffu) + __popc(ws & nm);   // local rank of elem 0
        unsigned baseA = (pv >> 16)     + __popc(wa & nm);
        unsigned sb = (ws >> nib) & 0xFu;
        unsigned ab = (wa >> nib) & 0xFu;
        float lsv[4], lav[4];
        #pragma unroll
        for (int j = 0; j < 4; ++j) {
            unsigned mj = (1u << j) - 1u;
            unsigned rs = baseS + __popc(sb & mj);
            float vs = rs < CAPS ? lsS[ofsS + rs]
                     : lsurf[(excS + rs) < ts_max ? (excS + rs) : ts_max];
            lsv[j] = ((sb >> j) & 1u) ? vs * alive + idle_term : NEG_PAD;
            unsigned ra = baseA + __popc(ab & mj);
            float va = ra < CAPA ? laS[ofsA + ra]
                     : lair[(excA + ra) < ta_max ? (excA + ra) : ta_max];
            lav[j] = ((ab >> j) & 1u) ? va * alive + idle_term : NEG_PAD;
        }
        const long long eb = base + h * 1024 + 4 * t;  // 16-B aligned
        float4a vls; vls.x = lsv[0]; vls.y = lsv[1]; vls.z = lsv[2]; vls.w = lsv[3];
        float4a vla; vla.x = lav[0]; vla.y = lav[1]; vla.z = lav[2]; vla.w = lav[3];
        __builtin_nontemporal_store(vls, (float4a*)(out_ls + eb));
        __builtin_nontemporal_store(vla, (float4a*)(out_la + eb));
    }
}

extern "C" void kernel_launch(void* const* d_in, const int* in_sizes, int n_in,
                              void* d_out, int out_size, void* d_ws, size_t ws_size,
                              hipStream_t stream)
{
    const float* rgb   = (const float*)d_in[0];
    const float* lsurf = (const float*)d_in[1];
    const float* lair  = (const float*)d_in[2];
    const float* idle  = (const float*)d_in[3];
    const int*   ms    = (const int*)d_in[4];   // bool -> int32 per harness contract
    const int*   ma    = (const int*)d_in[5];

    unsigned rgb_max = (unsigned)(in_sizes[0] / 3 - 1);
    unsigned ts_max  = (unsigned)(in_sizes[1] - 1);
    unsigned ta_max  = (unsigned)(in_sizes[2] - 1);

    float* out     = (float*)d_out;
    float* out_rgb = out;                  // (B,K,N,3)
    float* out_ls  = out + NTOT * 3;       // (B,K,N,1)
    float* out_la  = out_ls + NTOT;        // (B,K,N,1)

    // Workspace: totals (16 KB) then compressed masks (1 MB); both fully
    // rewritten by K1 every launch -> no init needed despite 0xAA poison.
    u64* totals = (u64*)d_ws;
    unsigned short* cmp = (unsigned short*)((char*)d_ws + 16384);

    count_kernel<<<NBLK, 256, 0, stream>>>(ms, ma, cmp, totals);
    expand_kernel<<<NBLK, 256, 0, stream>>>(rgb, lsurf, lair, idle, cmp, totals,
                                            rgb_max, ts_max, ta_max,
                                            out_rgb, out_ls, out_la);
}